// Round 2
// baseline (2830.744 us; speedup 1.0000x reference)
//
#include <hip/hip_runtime.h>

typedef unsigned short u16;
typedef unsigned int u32;
typedef __bf16 bf16x8 __attribute__((ext_vector_type(8)));
typedef float f32x4 __attribute__((ext_vector_type(4)));

#define BB 2
#define SS 2048
#define HH 2048
#define NHH 16
#define HDD 128

__device__ __forceinline__ float b2f(u16 u) {
  union { u32 i; float f; } v; v.i = ((u32)u) << 16; return v.f;
}
__device__ __forceinline__ u16 f2b(float f) {
  union { float f; u32 i; } v; v.f = f;
  u32 x = v.i;
  u32 r = (x + 0x7fffu + ((x >> 16) & 1u)) >> 16;
  return (u16)r;
}

// Fused f32 -> bf16 conversion for 5 tensors; blockIdx.y selects tensor.
__global__ __launch_bounds__(256) void cvt_kernel(
    const float* __restrict__ s0, u16* __restrict__ d0, int n0,
    const float* __restrict__ s1, u16* __restrict__ d1, int n1,
    const float* __restrict__ s2, u16* __restrict__ d2, int n2,
    const float* __restrict__ s3, u16* __restrict__ d3, int n3,
    const float* __restrict__ s4, u16* __restrict__ d4, int n4)
{
  const float* s; u16* d; int n;
  switch (blockIdx.y) {
    case 0: s = s0; d = d0; n = n0; break;
    case 1: s = s1; d = d1; n = n1; break;
    case 2: s = s2; d = d2; n = n2; break;
    case 3: s = s3; d = d3; n = n3; break;
    default: s = s4; d = d4; n = n4; break;
  }
  int nq = n >> 2;
  for (int q = blockIdx.x * 256 + threadIdx.x; q < nq; q += gridDim.x * 256) {
    float4 v = *(const float4*)(s + (size_t)q * 4);
    ushort4 o;
    o.x = f2b(v.x); o.y = f2b(v.y); o.z = f2b(v.z); o.w = f2b(v.w);
    *(ushort4*)(d + (size_t)q * 4) = o;
  }
}

// C = A[M,K](bf16) @ Bw[N,K](bf16)^T + bias(f32). OUT_F32 ? f32 store : bf16 store.
// 128x128 tile, BK=32, 256 threads = 4 waves (2x2 of 64x64), MFMA 16x16x32 bf16.
template<int OUT_F32>
__global__ __launch_bounds__(256) void gemm_bias_kernel(
    const u16* __restrict__ A, const u16* __restrict__ Bw,
    const float* __restrict__ bias, void* __restrict__ Cv,
    int M, int N, int K, int lda, int ldb, int ldc)
{
  __shared__ u16 As[4][128][8];
  __shared__ u16 Bs[4][128][8];
  const int t = threadIdx.x;
  const int m0 = blockIdx.y * 128;
  const int n0 = blockIdx.x * 128;
  const int lane = t & 63, wid = t >> 6;
  const int wm = (wid >> 1) * 64, wn = (wid & 1) * 64;
  const int quad = lane >> 4, lm = lane & 15;
  const int srow = t >> 2, schk = t & 3;

  f32x4 acc[4][4] = {};

  for (int k0 = 0; k0 < K; k0 += 32) {
    __syncthreads();
#pragma unroll
    for (int it = 0; it < 2; ++it) {
      int r = srow + it * 64;
      uint4 av = *(const uint4*)(A + (size_t)(m0 + r) * lda + k0 + schk * 8);
      *(uint4*)&As[schk][r][0] = av;
      int rn = n0 + r;
      uint4 bv = {0u, 0u, 0u, 0u};
      if (rn < N) bv = *(const uint4*)(Bw + (size_t)rn * ldb + k0 + schk * 8);
      *(uint4*)&Bs[schk][r][0] = bv;
    }
    __syncthreads();
    bf16x8 af[4], bf[4];
#pragma unroll
    for (int i = 0; i < 4; ++i) af[i] = *(const bf16x8*)&As[quad][wm + i * 16 + lm][0];
#pragma unroll
    for (int j = 0; j < 4; ++j) bf[j] = *(const bf16x8*)&Bs[quad][wn + j * 16 + lm][0];
#pragma unroll
    for (int i = 0; i < 4; ++i)
#pragma unroll
      for (int j = 0; j < 4; ++j)
        acc[i][j] = __builtin_amdgcn_mfma_f32_16x16x32_bf16(af[i], bf[j], acc[i][j], 0, 0, 0);
  }

  // C/D layout: col = lane&15, row = quad*4 + reg (m89/m91 verified)
#pragma unroll
  for (int i = 0; i < 4; ++i) {
    int gm = m0 + wm + i * 16 + quad * 4;
#pragma unroll
    for (int j = 0; j < 4; ++j) {
      int gn = n0 + wn + j * 16 + lm;
      if (gn < N) {
        float bsv = bias[gn];
        f32x4 a = acc[i][j];
        if (OUT_F32) {
          float* C = (float*)Cv;
#pragma unroll
          for (int rg = 0; rg < 4; ++rg)
            C[(size_t)(gm + rg) * ldc + gn] = a[rg] + bsv;
        } else {
          u16* C = (u16*)Cv;
#pragma unroll
          for (int rg = 0; rg < 4; ++rg)
            C[(size_t)(gm + rg) * ldc + gn] = f2b(a[rg] + bsv);
        }
      }
    }
  }
}

// In-place RoPE on q,k first ROT=32 dims of each head. One thread per (b,s,h,i<16).
__global__ __launch_bounds__(256) void rope_kernel(u16* __restrict__ qkv)
{
  int idx = blockIdx.x * 256 + threadIdx.x;   // B*S*NH*16 = 1048576
  int i = idx & 15;
  int h = (idx >> 4) & 15;
  int rs = idx >> 8;                          // b*S + s, 0..4095
  int s = rs & (SS - 1);
  // inv_freq = 10000^(-2i/32) = 2^(-i*log2(10000)/16)
  float inv_freq = exp2f(-(float)i * 0.8304820237218406f);
  float ang = (float)s * inv_freq;
  float sn, c;
  sincosf(ang, &sn, &c);
  size_t base = (size_t)rs * 6144 + (size_t)h * 128;
  {
    float x0 = b2f(qkv[base + i]), x1 = b2f(qkv[base + i + 16]);
    qkv[base + i]      = f2b(x0 * c - x1 * sn);
    qkv[base + i + 16] = f2b(x1 * c + x0 * sn);
  }
  {
    size_t kb = base + 2048;
    float x0 = b2f(qkv[kb + i]), x1 = b2f(qkv[kb + i + 16]);
    qkv[kb + i]      = f2b(x0 * c - x1 * sn);
    qkv[kb + i + 16] = f2b(x1 * c + x0 * sn);
  }
}

// Causal flash attention, vector fp32. Block=256 threads: one (b,h), 32 query rows;
// K/V tiles of 64 staged in LDS. Thread t: row r8=t>>3, group cg=t&7.
__global__ __launch_bounds__(256) void attn_kernel(const u16* __restrict__ qkv,
                                                   const u16* __restrict__ vr,
                                                   u16* __restrict__ out)
{
  __shared__ u16 Qt[32 * 132];
  __shared__ u16 Kt[64 * 132];
  __shared__ u16 Vt[64 * 132];
  __shared__ float Sc[32 * 65];
  __shared__ float mrow[32], lrow[32], arow[32];

  const int t = threadIdx.x;
  const int bh = blockIdx.y;
  const int b = bh >> 4, h = bh & 15;
  const int q0 = blockIdx.x * 32;

  {
    int r = t >> 3, col = (t & 7) * 16;
    const u16* src = qkv + (size_t)(b * SS + q0 + r) * 6144 + h * 128 + col;
    u16* dst = &Qt[r * 132 + col];
#pragma unroll
    for (int u = 0; u < 4; ++u)
      *(uint2*)(dst + u * 4) = *(const uint2*)(src + u * 4);
  }
  if (t < 32) { mrow[t] = -1e30f; lrow[t] = 0.0f; }

  float Oa[16];
#pragma unroll
  for (int j = 0; j < 16; ++j) Oa[j] = 0.0f;

  const int r8 = t >> 3;
  const int cg = t & 7;
  const int dd = cg * 16;
  const float scale = 0.08838834764831845f;  // 1/sqrt(128)

  for (int kb = 0; kb <= q0 + 31; kb += 64) {
    __syncthreads();
    {
      int r = t >> 2, col = (t & 3) * 32;
      const u16* ksrc = qkv + (size_t)(b * SS + kb + r) * 6144 + 2048 + h * 128 + col;
      const u16* vsrc = vr + (size_t)(b * SS + kb + r) * 2048 + h * 128 + col;
      u16* kd = &Kt[r * 132 + col];
      u16* vd = &Vt[r * 132 + col];
#pragma unroll
      for (int u = 0; u < 8; ++u) {
        *(uint2*)(kd + u * 4) = *(const uint2*)(ksrc + u * 4);
        *(uint2*)(vd + u * 4) = *(const uint2*)(vsrc + u * 4);
      }
    }
    __syncthreads();

    float sc[8];
#pragma unroll
    for (int j = 0; j < 8; ++j) sc[j] = 0.0f;
    for (int d = 0; d < 128; d += 4) {
      ushort4 qv = *(const ushort4*)&Qt[r8 * 132 + d];
      float qa = b2f(qv.x), qb = b2f(qv.y), qc = b2f(qv.z), qd = b2f(qv.w);
#pragma unroll
      for (int j = 0; j < 8; ++j) {
        ushort4 kv = *(const ushort4*)&Kt[(cg * 8 + j) * 132 + d];
        sc[j] += qa * b2f(kv.x) + qb * b2f(kv.y) + qc * b2f(kv.z) + qd * b2f(kv.w);
      }
    }
#pragma unroll
    for (int j = 0; j < 8; ++j) {
      int kpos = kb + cg * 8 + j;
      float v = sc[j] * scale;
      if (kpos > q0 + r8) v = -1e30f;
      Sc[r8 * 65 + cg * 8 + j] = v;
    }
    __syncthreads();

    if (t < 32) {
      float m_old = mrow[t];
      float mx = m_old;
      for (int c = 0; c < 64; ++c) mx = fmaxf(mx, Sc[t * 65 + c]);
      float alpha = __expf(m_old - mx);
      float sum = 0.0f;
      for (int c = 0; c < 64; ++c) {
        float p = __expf(Sc[t * 65 + c] - mx);
        Sc[t * 65 + c] = p;
        sum += p;
      }
      lrow[t] = lrow[t] * alpha + sum;
      mrow[t] = mx;
      arow[t] = alpha;
    }
    __syncthreads();

    float alpha = arow[r8];
#pragma unroll
    for (int j = 0; j < 16; ++j) Oa[j] *= alpha;
    for (int c = 0; c < 64; ++c) {
      float p = Sc[r8 * 65 + c];
      const u16* vrow = &Vt[c * 132 + dd];
#pragma unroll
      for (int u = 0; u < 4; ++u) {
        ushort4 vv = *(const ushort4*)(vrow + u * 4);
        Oa[u * 4 + 0] += p * b2f(vv.x);
        Oa[u * 4 + 1] += p * b2f(vv.y);
        Oa[u * 4 + 2] += p * b2f(vv.z);
        Oa[u * 4 + 3] += p * b2f(vv.w);
      }
    }
  }

  float inv_l = 1.0f / lrow[r8];
  u16* dst = out + (size_t)(b * SS + q0 + r8) * 2048 + h * 128 + dd;
#pragma unroll
  for (int j = 0; j < 16; ++j) dst[j] = f2b(Oa[j] * inv_l);
}

extern "C" void kernel_launch(void* const* d_in, const int* in_sizes, int n_in,
                              void* d_out, int out_size, void* d_ws, size_t ws_size,
                              hipStream_t stream)
{
  (void)in_sizes; (void)n_in; (void)out_size; (void)ws_size;
  const float* X    = (const float*)d_in[0];
  const float* Wqkv = (const float*)d_in[1];
  const float* bqkv = (const float*)d_in[2];
  const float* Wc   = (const float*)d_in[3];
  const float* bc   = (const float*)d_in[4];
  const float* Wr   = (const float*)d_in[5];
  const float* br   = (const float*)d_in[6];
  const float* Wd   = (const float*)d_in[7];
  const float* bd   = (const float*)d_in[8];
  float* out = (float*)d_out;

  // Workspace layout (aliased, lifetimes disjoint):
  //  [0,            50331648)  QKV   bf16 4096x6144
  //  [50331648,     52953088)  Cb    bf16 4096x320
  //  [52953088,     78118912)  Wqkvb bf16 6144x2048 (steps 1-2) / Vr bf16 4096x2048 (steps 5-6)
  //  [78118912,     94896128)  Xb    bf16 4096x2048 (steps 1-2) / AO bf16 4096x2048 (steps 6-7)
  //  [94896128,     96206848)  Wcb   bf16 320x2048
  //  [96206848,     97517568)  Wrb   bf16 2048x320
  //  [97517568,    105906176)  Wdb   bf16 2048x2048
  char* ws = (char*)d_ws;
  u16* QKV   = (u16*)(ws);
  u16* Cb    = (u16*)(ws + 50331648);
  u16* Wqkvb = (u16*)(ws + 52953088);
  u16* Vr    = (u16*)(ws + 52953088);
  u16* Xb    = (u16*)(ws + 78118912);
  u16* AO    = (u16*)(ws + 78118912);
  u16* Wcb   = (u16*)(ws + 94896128);
  u16* Wrb   = (u16*)(ws + 96206848);
  u16* Wdb   = (u16*)(ws + 97517568);

  dim3 blk(256);

  // 0. convert f32 inputs -> bf16
  cvt_kernel<<<dim3(512, 5), blk, 0, stream>>>(
      X, Xb, 4096 * 2048,
      Wqkv, Wqkvb, 6144 * 2048,
      Wc, Wcb, 320 * 2048,
      Wr, Wrb, 2048 * 320,
      Wd, Wdb, 2048 * 2048);

  // 1. QKV projection
  gemm_bias_kernel<0><<<dim3(48, 32), blk, 0, stream>>>(Xb, Wqkvb, bqkv, QKV,
                                                        4096, 6144, 2048, 2048, 2048, 6144);
  // 2. RoPE in place on q,k
  rope_kernel<<<dim3(4096), blk, 0, stream>>>(QKV);
  // 3. C = V_hidden @ Wc^T + bc
  gemm_bias_kernel<0><<<dim3(3, 32), blk, 0, stream>>>(QKV + 4096, Wcb, bc, Cb,
                                                       4096, 320, 2048, 6144, 2048, 320);
  // 4. Vr = C @ Wr^T + br
  gemm_bias_kernel<0><<<dim3(16, 32), blk, 0, stream>>>(Cb, Wrb, br, Vr,
                                                        4096, 2048, 320, 320, 320, 2048);
  // 5. causal attention -> hidden layout (bf16)
  attn_kernel<<<dim3(64, 32), blk, 0, stream>>>(QKV, Vr, AO);
  // 6. output projection -> f32 d_out
  gemm_bias_kernel<1><<<dim3(16, 32), blk, 0, stream>>>(AO, Wdb, bd, out,
                                                        4096, 2048, 2048, 2048, 2048, 2048);
}

// Round 3
// 691.580 us; speedup vs baseline: 4.0932x; 4.0932x over previous
//
#include <hip/hip_runtime.h>

typedef unsigned short u16;
typedef unsigned int u32;
typedef __bf16 bf16x8 __attribute__((ext_vector_type(8)));
typedef float f32x4 __attribute__((ext_vector_type(4)));

#define BB 2
#define SS 2048
#define HH 2048
#define NHH 16
#define HDD 128

__device__ __forceinline__ float b2f(u16 u) {
  union { u32 i; float f; } v; v.i = ((u32)u) << 16; return v.f;
}
__device__ __forceinline__ u16 f2b(float f) {
  union { float f; u32 i; } v; v.f = f;
  u32 x = v.i;
  u32 r = (x + 0x7fffu + ((x >> 16) & 1u)) >> 16;
  return (u16)r;
}

// Fused f32 -> bf16 conversion for 5 tensors; blockIdx.y selects tensor.
__global__ __launch_bounds__(256) void cvt_kernel(
    const float* __restrict__ s0, u16* __restrict__ d0, int n0,
    const float* __restrict__ s1, u16* __restrict__ d1, int n1,
    const float* __restrict__ s2, u16* __restrict__ d2, int n2,
    const float* __restrict__ s3, u16* __restrict__ d3, int n3,
    const float* __restrict__ s4, u16* __restrict__ d4, int n4)
{
  const float* s; u16* d; int n;
  switch (blockIdx.y) {
    case 0: s = s0; d = d0; n = n0; break;
    case 1: s = s1; d = d1; n = n1; break;
    case 2: s = s2; d = d2; n = n2; break;
    case 3: s = s3; d = d3; n = n3; break;
    default: s = s4; d = d4; n = n4; break;
  }
  int nq = n >> 2;
  for (int q = blockIdx.x * 256 + threadIdx.x; q < nq; q += gridDim.x * 256) {
    float4 v = *(const float4*)(s + (size_t)q * 4);
    ushort4 o;
    o.x = f2b(v.x); o.y = f2b(v.y); o.z = f2b(v.z); o.w = f2b(v.w);
    *(ushort4*)(d + (size_t)q * 4) = o;
  }
}

// C = A[M,K](bf16) @ Bw[N,K](bf16)^T + bias(f32). OUT_F32 ? f32 store : bf16 store.
template<int OUT_F32>
__global__ __launch_bounds__(256) void gemm_bias_kernel(
    const u16* __restrict__ A, const u16* __restrict__ Bw,
    const float* __restrict__ bias, void* __restrict__ Cv,
    int M, int N, int K, int lda, int ldb, int ldc)
{
  __shared__ u16 As[4][128][8];
  __shared__ u16 Bs[4][128][8];
  const int t = threadIdx.x;
  const int m0 = blockIdx.y * 128;
  const int n0 = blockIdx.x * 128;
  const int lane = t & 63, wid = t >> 6;
  const int wm = (wid >> 1) * 64, wn = (wid & 1) * 64;
  const int quad = lane >> 4, lm = lane & 15;
  const int srow = t >> 2, schk = t & 3;

  f32x4 acc[4][4] = {};

  for (int k0 = 0; k0 < K; k0 += 32) {
    __syncthreads();
#pragma unroll
    for (int it = 0; it < 2; ++it) {
      int r = srow + it * 64;
      uint4 av = *(const uint4*)(A + (size_t)(m0 + r) * lda + k0 + schk * 8);
      *(uint4*)&As[schk][r][0] = av;
      int rn = n0 + r;
      uint4 bv = {0u, 0u, 0u, 0u};
      if (rn < N) bv = *(const uint4*)(Bw + (size_t)rn * ldb + k0 + schk * 8);
      *(uint4*)&Bs[schk][r][0] = bv;
    }
    __syncthreads();
    bf16x8 af[4], bf[4];
#pragma unroll
    for (int i = 0; i < 4; ++i) af[i] = *(const bf16x8*)&As[quad][wm + i * 16 + lm][0];
#pragma unroll
    for (int j = 0; j < 4; ++j) bf[j] = *(const bf16x8*)&Bs[quad][wn + j * 16 + lm][0];
#pragma unroll
    for (int i = 0; i < 4; ++i)
#pragma unroll
      for (int j = 0; j < 4; ++j)
        acc[i][j] = __builtin_amdgcn_mfma_f32_16x16x32_bf16(af[i], bf[j], acc[i][j], 0, 0, 0);
  }

#pragma unroll
  for (int i = 0; i < 4; ++i) {
    int gm = m0 + wm + i * 16 + quad * 4;
#pragma unroll
    for (int j = 0; j < 4; ++j) {
      int gn = n0 + wn + j * 16 + lm;
      if (gn < N) {
        float bsv = bias[gn];
        f32x4 a = acc[i][j];
        if (OUT_F32) {
          float* C = (float*)Cv;
#pragma unroll
          for (int rg = 0; rg < 4; ++rg)
            C[(size_t)(gm + rg) * ldc + gn] = a[rg] + bsv;
        } else {
          u16* C = (u16*)Cv;
#pragma unroll
          for (int rg = 0; rg < 4; ++rg)
            C[(size_t)(gm + rg) * ldc + gn] = f2b(a[rg] + bsv);
        }
      }
    }
  }
}

// In-place RoPE on q,k first ROT=32 dims of each head.
__global__ __launch_bounds__(256) void rope_kernel(u16* __restrict__ qkv)
{
  int idx = blockIdx.x * 256 + threadIdx.x;   // B*S*NH*16 = 1048576
  int i = idx & 15;
  int h = (idx >> 4) & 15;
  int rs = idx >> 8;
  int s = rs & (SS - 1);
  float inv_freq = exp2f(-(float)i * 0.8304820237218406f);
  float ang = (float)s * inv_freq;
  float sn, c;
  sincosf(ang, &sn, &c);
  size_t base = (size_t)rs * 6144 + (size_t)h * 128;
  {
    float x0 = b2f(qkv[base + i]), x1 = b2f(qkv[base + i + 16]);
    qkv[base + i]      = f2b(x0 * c - x1 * sn);
    qkv[base + i + 16] = f2b(x1 * c + x0 * sn);
  }
  {
    size_t kb = base + 2048;
    float x0 = b2f(qkv[kb + i]), x1 = b2f(qkv[kb + i + 16]);
    qkv[kb + i]      = f2b(x0 * c - x1 * sn);
    qkv[kb + i + 16] = f2b(x1 * c + x0 * sn);
  }
}

// Vr[4096][2048] -> VrT[32][128][2048]: VrT[b*16+h][d][s] = Vr[b*2048+s][h*128+d]
__global__ __launch_bounds__(256) void transpose_v_kernel(const u16* __restrict__ vr,
                                                          u16* __restrict__ vrt)
{
  __shared__ u16 L[64][72];
  const int t = threadIdx.x;
  const int s0 = blockIdx.x * 64;
  const int d0 = blockIdx.y * 64;
  const int bh = blockIdx.z; const int b = bh >> 4, h = bh & 15;
#pragma unroll
  for (int it = 0; it < 2; ++it) {
    int c = t + it * 256;
    int sl = c >> 3, d8 = c & 7;
    *(uint4*)&L[sl][d8 * 8] =
      *(const uint4*)(vr + (size_t)(b * 2048 + s0 + sl) * 2048 + h * 128 + d0 + d8 * 8);
  }
  __syncthreads();
#pragma unroll
  for (int it = 0; it < 2; ++it) {
    int c = t + it * 256;
    int d = c >> 3, s8 = c & 7;
    u16 tmp[8];
#pragma unroll
    for (int r = 0; r < 8; ++r) tmp[r] = L[s8 * 8 + r][d];
    uint4 o;
    o.x = (u32)tmp[0] | ((u32)tmp[1] << 16);
    o.y = (u32)tmp[2] | ((u32)tmp[3] << 16);
    o.z = (u32)tmp[4] | ((u32)tmp[5] << 16);
    o.w = (u32)tmp[6] | ((u32)tmp[7] << 16);
    *(uint4*)(vrt + ((size_t)bh * 128 + d0 + d) * 2048 + s0 + s8 * 8) = o;
  }
}

// MFMA causal flash attention. Block = 256 thr = 4 waves, one (b,h), 64 q-rows
// (wave w owns rows qw=q0+w*16..+15). K/V tiles of 64. All frag reads are
// ds_read_b128 with 16-consecutive-lanes -> 16-consecutive-16B (conflict-free).
__global__ __launch_bounds__(256) void attn_mfma_kernel(
    const u16* __restrict__ qkv, const u16* __restrict__ vrt, u16* __restrict__ out)
{
  __shared__ u16 Kt[16][64][8];    // [dq][kp][j]  = K[kb+kp][dq*8+j]       16KB
  __shared__ u16 Vt[8][128][8];    // [kq][d][j]   = V[kb+kq*8+j][d]        16KB
  __shared__ u16 Pa[4][8][16][8];  // [wave][kq][q][j] = P[q][kq*8+j]        8KB

  const int t = threadIdx.x;
  const int lane = t & 63, w = t >> 6;
  const int quad = lane >> 4, lm = lane & 15;
  const int bh = blockIdx.y; const int b = bh >> 4, h = bh & 15;
  const int qt = gridDim.x - 1 - blockIdx.x;   // heavy tiles first
  const int q0 = qt * 64;
  const int qw = q0 + w * 16;

  // Q A-fragments held in registers: Q[qw+lm][dc*32+quad*8+j]
  bf16x8 qf[4];
  {
    const u16* qsrc = qkv + (size_t)(b * SS + qw + lm) * 6144 + h * 128 + quad * 8;
#pragma unroll
    for (int dc = 0; dc < 4; ++dc) qf[dc] = *(const bf16x8*)(qsrc + dc * 32);
  }

  f32x4 Oa[8] = {};                 // [dt]: O[q=quad*4+reg][d=dt*16+lm]
  float mrow[4], lrow[4];
#pragma unroll
  for (int r = 0; r < 4; ++r) { mrow[r] = -1e30f; lrow[r] = 0.f; }

  const float scale = 0.08838834764831845f;  // 1/sqrt(128)
  const int nkt = qt + 1;
  const u16* kbase = qkv + (size_t)b * SS * 6144 + 2048 + h * 128;
  const u16* vbase = vrt + (size_t)bh * 128 * 2048;

  for (int kt = 0; kt < nkt; ++kt) {
    const int kb = kt * 64;
    __syncthreads();
    // stage K (1024 x 16B) and V^T (1024 x 16B)
#pragma unroll
    for (int it = 0; it < 4; ++it) {
      int c = t + it * 256;
      int kp = c & 63, dq = c >> 6;
      *(uint4*)&Kt[dq][kp][0] =
          *(const uint4*)(kbase + (size_t)(kb + kp) * 6144 + dq * 8);
      int d = c & 127, kq = c >> 7;
      *(uint4*)&Vt[kq][d][0] =
          *(const uint4*)(vbase + (size_t)d * 2048 + kb + kq * 8);
    }
    __syncthreads();

    // S = Q K^T : per wave 16 q x 64 kp
    f32x4 sa[4] = {};
#pragma unroll
    for (int ct = 0; ct < 4; ++ct) {
#pragma unroll
      for (int dc = 0; dc < 4; ++dc) {
        bf16x8 kf = *(const bf16x8*)&Kt[dc * 4 + quad][ct * 16 + lm][0];
        sa[ct] = __builtin_amdgcn_mfma_f32_16x16x32_bf16(qf[dc], kf, sa[ct], 0, 0, 0);
      }
    }
#pragma unroll
    for (int ct = 0; ct < 4; ++ct)
#pragma unroll
      for (int r = 0; r < 4; ++r) sa[ct][r] *= scale;

    if (kt == nkt - 1) {  // diagonal tile: mask kpos > qrow
#pragma unroll
      for (int ct = 0; ct < 4; ++ct) {
        int kpos = kb + ct * 16 + lm;
#pragma unroll
        for (int r = 0; r < 4; ++r)
          if (kpos > qw + quad * 4 + r) sa[ct][r] = -1e30f;
      }
    }

    // online softmax: rows = (quad, r); 16 lanes of a quad share 64 cols
    float alpha[4];
#pragma unroll
    for (int r = 0; r < 4; ++r) {
      float mx = fmaxf(fmaxf(sa[0][r], sa[1][r]), fmaxf(sa[2][r], sa[3][r]));
#pragma unroll
      for (int off = 1; off < 16; off <<= 1)
        mx = fmaxf(mx, __shfl_xor(mx, off, 64));
      float mnew = fmaxf(mrow[r], mx);
      alpha[r] = __expf(mrow[r] - mnew);
      float s = 0.f;
#pragma unroll
      for (int ct = 0; ct < 4; ++ct) {
        float p = __expf(sa[ct][r] - mnew);
        sa[ct][r] = p;
        s += p;
      }
#pragma unroll
      for (int off = 1; off < 16; off <<= 1)
        s += __shfl_xor(s, off, 64);
      lrow[r] = lrow[r] * alpha[r] + s;
      mrow[r] = mnew;
    }

#pragma unroll
    for (int dt = 0; dt < 8; ++dt)
#pragma unroll
      for (int r = 0; r < 4; ++r) Oa[dt][r] *= alpha[r];

    // P (C-layout) -> LDS in A-frag-major layout (wave-private, no barrier)
#pragma unroll
    for (int ct = 0; ct < 4; ++ct) {
      int kq = ct * 2 + (lm >> 3), j = lm & 7;
#pragma unroll
      for (int r = 0; r < 4; ++r)
        Pa[w][kq][quad * 4 + r][j] = f2b(sa[ct][r]);
    }
    bf16x8 pf0 = *(const bf16x8*)&Pa[w][quad][lm][0];
    bf16x8 pf1 = *(const bf16x8*)&Pa[w][4 + quad][lm][0];

    // O += P V : V^T B-frags from Vt
#pragma unroll
    for (int dt = 0; dt < 8; ++dt) {
      bf16x8 vf0 = *(const bf16x8*)&Vt[quad][dt * 16 + lm][0];
      bf16x8 vf1 = *(const bf16x8*)&Vt[4 + quad][dt * 16 + lm][0];
      Oa[dt] = __builtin_amdgcn_mfma_f32_16x16x32_bf16(pf0, vf0, Oa[dt], 0, 0, 0);
      Oa[dt] = __builtin_amdgcn_mfma_f32_16x16x32_bf16(pf1, vf1, Oa[dt], 0, 0, 0);
    }
  }

  float inv[4];
#pragma unroll
  for (int r = 0; r < 4; ++r) inv[r] = 1.0f / lrow[r];
  u16* dst = out + (size_t)(b * SS + qw + quad * 4) * 2048 + h * 128 + lm;
#pragma unroll
  for (int r = 0; r < 4; ++r)
#pragma unroll
    for (int dt = 0; dt < 8; ++dt)
      dst[(size_t)r * 2048 + dt * 16] = f2b(Oa[dt][r] * inv[r]);
}

extern "C" void kernel_launch(void* const* d_in, const int* in_sizes, int n_in,
                              void* d_out, int out_size, void* d_ws, size_t ws_size,
                              hipStream_t stream)
{
  (void)in_sizes; (void)n_in; (void)out_size; (void)ws_size;
  const float* X    = (const float*)d_in[0];
  const float* Wqkv = (const float*)d_in[1];
  const float* bqkv = (const float*)d_in[2];
  const float* Wc   = (const float*)d_in[3];
  const float* bc   = (const float*)d_in[4];
  const float* Wr   = (const float*)d_in[5];
  const float* br   = (const float*)d_in[6];
  const float* Wd   = (const float*)d_in[7];
  const float* bd   = (const float*)d_in[8];
  float* out = (float*)d_out;

  // Workspace (105,906,176 B total, same as passing R2 layout):
  //  A: [0, 50331648)            QKV bf16 4096x6144                 [steps 1-5]
  //  B: [50331648, 67108864)     Xb [cvt-1] / Vr [4-T] / AO [5-6]
  //  C: [67108864, 92274688)     Wqkvb 25MB [cvt-1] / VrT 16MB [T-5]
  //  D: [92274688, ...)          Wcb, Wrb, Cb, Wdb
  char* ws = (char*)d_ws;
  u16* QKV   = (u16*)(ws);
  u16* Xb    = (u16*)(ws + 50331648);
  u16* Vr    = (u16*)(ws + 50331648);
  u16* AO    = (u16*)(ws + 50331648);
  u16* Wqkvb = (u16*)(ws + 67108864);
  u16* VrT   = (u16*)(ws + 67108864);
  u16* Wcb   = (u16*)(ws + 92274688);
  u16* Wrb   = (u16*)(ws + 93585408);
  u16* Cb    = (u16*)(ws + 94896128);
  u16* Wdb   = (u16*)(ws + 97517568);

  dim3 blk(256);

  // 0. convert f32 inputs -> bf16
  cvt_kernel<<<dim3(512, 5), blk, 0, stream>>>(
      X, Xb, 4096 * 2048,
      Wqkv, Wqkvb, 6144 * 2048,
      Wc, Wcb, 320 * 2048,
      Wr, Wrb, 2048 * 320,
      Wd, Wdb, 2048 * 2048);

  // 1. QKV projection
  gemm_bias_kernel<0><<<dim3(48, 32), blk, 0, stream>>>(Xb, Wqkvb, bqkv, QKV,
                                                        4096, 6144, 2048, 2048, 2048, 6144);
  // 2. RoPE in place on q,k
  rope_kernel<<<dim3(4096), blk, 0, stream>>>(QKV);
  // 3. C = V_hidden @ Wc^T + bc
  gemm_bias_kernel<0><<<dim3(3, 32), blk, 0, stream>>>(QKV + 4096, Wcb, bc, Cb,
                                                       4096, 320, 2048, 6144, 2048, 320);
  // 4. Vr = C @ Wr^T + br
  gemm_bias_kernel<0><<<dim3(16, 32), blk, 0, stream>>>(Cb, Wrb, br, Vr,
                                                        4096, 2048, 320, 320, 320, 2048);
  // T. transpose V for attention B-fragments
  transpose_v_kernel<<<dim3(32, 2, 32), blk, 0, stream>>>(Vr, VrT);
  // 5. MFMA causal flash attention -> AO (bf16, hidden layout)
  attn_mfma_kernel<<<dim3(32, 32), blk, 0, stream>>>(QKV, VrT, AO);
  // 6. output projection -> f32 d_out
  gemm_bias_kernel<1><<<dim3(16, 32), blk, 0, stream>>>(AO, Wdb, bd, out,
                                                        4096, 2048, 2048, 2048, 2048, 2048);
}

// Round 4
// 672.665 us; speedup vs baseline: 4.2083x; 1.0281x over previous
//
#include <hip/hip_runtime.h>

typedef unsigned short u16;
typedef unsigned int u32;
typedef __bf16 bf16x8 __attribute__((ext_vector_type(8)));
typedef float f32x4 __attribute__((ext_vector_type(4)));

#define BB 2
#define SS 2048
#define HH 2048
#define NHH 16
#define HDD 128

__device__ __forceinline__ float b2f(u16 u) {
  union { u32 i; float f; } v; v.i = ((u32)u) << 16; return v.f;
}
__device__ __forceinline__ u16 f2b(float f) {
  union { float f; u32 i; } v; v.f = f;
  u32 x = v.i;
  u32 r = (x + 0x7fffu + ((x >> 16) & 1u)) >> 16;
  return (u16)r;
}

// async global->LDS 16B: LDS dest = wave-uniform base + lane*16
__device__ __forceinline__ void gload_lds16(const u16* g, u16* l) {
  __builtin_amdgcn_global_load_lds(
      (const __attribute__((address_space(1))) u32*)g,
      (__attribute__((address_space(3))) u32*)l, 16, 0, 0);
}

// Fused f32 -> bf16 conversion for 5 tensors; blockIdx.y selects tensor.
__global__ __launch_bounds__(256) void cvt_kernel(
    const float* __restrict__ s0, u16* __restrict__ d0, int n0,
    const float* __restrict__ s1, u16* __restrict__ d1, int n1,
    const float* __restrict__ s2, u16* __restrict__ d2, int n2,
    const float* __restrict__ s3, u16* __restrict__ d3, int n3,
    const float* __restrict__ s4, u16* __restrict__ d4, int n4)
{
  const float* s; u16* d; int n;
  switch (blockIdx.y) {
    case 0: s = s0; d = d0; n = n0; break;
    case 1: s = s1; d = d1; n = n1; break;
    case 2: s = s2; d = d2; n = n2; break;
    case 3: s = s3; d = d3; n = n3; break;
    default: s = s4; d = d4; n = n4; break;
  }
  int nq = n >> 2;
  for (int q = blockIdx.x * 256 + threadIdx.x; q < nq; q += gridDim.x * 256) {
    float4 v = *(const float4*)(s + (size_t)q * 4);
    ushort4 o;
    o.x = f2b(v.x); o.y = f2b(v.y); o.z = f2b(v.z); o.w = f2b(v.w);
    *(ushort4*)(d + (size_t)q * 4) = o;
  }
}

// C = A[M,K](bf16) @ Bw[N,K](bf16)^T + bias(f32). OUT_F32 ? f32 : bf16 store.
// 128x128 tile, BK=32, 256 thr = 4 waves. Staging via global_load_lds width=16
// (m97): LDS chunk index = schk*128 + row, wave-uniform base + lane*16.
template<int OUT_F32>
__global__ __launch_bounds__(256) void gemm_bias_kernel(
    const u16* __restrict__ A, const u16* __restrict__ Bw,
    const float* __restrict__ bias, void* __restrict__ Cv,
    int M, int N, int K, int lda, int ldb, int ldc)
{
  __shared__ u16 Asf[4 * 128 * 8];
  __shared__ u16 Bsf[4 * 128 * 8];
  const int t = threadIdx.x;
  const int m0 = blockIdx.y * 128;
  const int n0 = blockIdx.x * 128;
  const int lane = t & 63, wid = t >> 6;
  const int wm = (wid >> 1) * 64, wn = (wid & 1) * 64;
  const int quad = lane >> 4, lm = lane & 15;

  f32x4 acc[4][4] = {};

  for (int k0 = 0; k0 < K; k0 += 32) {
    __syncthreads();
#pragma unroll
    for (int it = 0; it < 2; ++it) {
      int i0 = it * 256 + wid * 64;      // wave-uniform chunk base
      int schk = i0 >> 7;                // k-chunk 0..3
      int rbase = i0 & 127;              // 0 or 64
      int r = rbase + lane;
      gload_lds16(A + (size_t)(m0 + r) * lda + k0 + schk * 8, &Asf[(size_t)i0 * 8]);
      int rn = n0 + r;
      if (rn < N) {
        gload_lds16(Bw + (size_t)rn * ldb + k0 + schk * 8, &Bsf[(size_t)i0 * 8]);
      } else {
        uint4 z = {0u, 0u, 0u, 0u};
        *(uint4*)&Bsf[(size_t)(i0 + lane) * 8] = z;
      }
    }
    __syncthreads();
    bf16x8 af[4], bf[4];
#pragma unroll
    for (int i = 0; i < 4; ++i)
      af[i] = *(const bf16x8*)&Asf[(size_t)(quad * 128 + wm + i * 16 + lm) * 8];
#pragma unroll
    for (int j = 0; j < 4; ++j)
      bf[j] = *(const bf16x8*)&Bsf[(size_t)(quad * 128 + wn + j * 16 + lm) * 8];
#pragma unroll
    for (int i = 0; i < 4; ++i)
#pragma unroll
      for (int j = 0; j < 4; ++j)
        acc[i][j] = __builtin_amdgcn_mfma_f32_16x16x32_bf16(af[i], bf[j], acc[i][j], 0, 0, 0);
  }

#pragma unroll
  for (int i = 0; i < 4; ++i) {
    int gm = m0 + wm + i * 16 + quad * 4;
#pragma unroll
    for (int j = 0; j < 4; ++j) {
      int gn = n0 + wn + j * 16 + lm;
      if (gn < N) {
        float bsv = bias[gn];
        f32x4 a = acc[i][j];
        if (OUT_F32) {
          float* C = (float*)Cv;
#pragma unroll
          for (int rg = 0; rg < 4; ++rg)
            C[(size_t)(gm + rg) * ldc + gn] = a[rg] + bsv;
        } else {
          u16* C = (u16*)Cv;
#pragma unroll
          for (int rg = 0; rg < 4; ++rg)
            C[(size_t)(gm + rg) * ldc + gn] = f2b(a[rg] + bsv);
        }
      }
    }
  }
}

// In-place RoPE on q,k first ROT=32 dims of each head.
__global__ __launch_bounds__(256) void rope_kernel(u16* __restrict__ qkv)
{
  int idx = blockIdx.x * 256 + threadIdx.x;   // B*S*NH*16 = 1048576
  int i = idx & 15;
  int h = (idx >> 4) & 15;
  int rs = idx >> 8;
  int s = rs & (SS - 1);
  float inv_freq = exp2f(-(float)i * 0.8304820237218406f);
  float ang = (float)s * inv_freq;
  float sn, c;
  sincosf(ang, &sn, &c);
  size_t base = (size_t)rs * 6144 + (size_t)h * 128;
  {
    float x0 = b2f(qkv[base + i]), x1 = b2f(qkv[base + i + 16]);
    qkv[base + i]      = f2b(x0 * c - x1 * sn);
    qkv[base + i + 16] = f2b(x1 * c + x0 * sn);
  }
  {
    size_t kb = base + 2048;
    float x0 = b2f(qkv[kb + i]), x1 = b2f(qkv[kb + i + 16]);
    qkv[kb + i]      = f2b(x0 * c - x1 * sn);
    qkv[kb + i + 16] = f2b(x1 * c + x0 * sn);
  }
}

// Vr[4096][2048] -> VrT[32][128][2048]: VrT[b*16+h][d][s] = Vr[b*2048+s][h*128+d]
__global__ __launch_bounds__(256) void transpose_v_kernel(const u16* __restrict__ vr,
                                                          u16* __restrict__ vrt)
{
  __shared__ u16 L[64][72];
  const int t = threadIdx.x;
  const int s0 = blockIdx.x * 64;
  const int d0 = blockIdx.y * 64;
  const int bh = blockIdx.z; const int b = bh >> 4, h = bh & 15;
#pragma unroll
  for (int it = 0; it < 2; ++it) {
    int c = t + it * 256;
    int sl = c >> 3, d8 = c & 7;
    *(uint4*)&L[sl][d8 * 8] =
      *(const uint4*)(vr + (size_t)(b * 2048 + s0 + sl) * 2048 + h * 128 + d0 + d8 * 8);
  }
  __syncthreads();
#pragma unroll
  for (int it = 0; it < 2; ++it) {
    int c = t + it * 256;
    int d = c >> 3, s8 = c & 7;
    u16 tmp[8];
#pragma unroll
    for (int r = 0; r < 8; ++r) tmp[r] = L[s8 * 8 + r][d];
    uint4 o;
    o.x = (u32)tmp[0] | ((u32)tmp[1] << 16);
    o.y = (u32)tmp[2] | ((u32)tmp[3] << 16);
    o.z = (u32)tmp[4] | ((u32)tmp[5] << 16);
    o.w = (u32)tmp[6] | ((u32)tmp[7] << 16);
    *(uint4*)(vrt + ((size_t)bh * 128 + d0 + d) * 2048 + s0 + s8 * 8) = o;
  }
}

// MFMA causal flash attention. Block = 4 waves, one (b,h), 64 q-rows.
// Staging now row-coalesced; K in XOR-swizzled flat LDS (chunk = kp*16 + (dq^(kp&15))).
__global__ __launch_bounds__(256) void attn_mfma_kernel(
    const u16* __restrict__ qkv, const u16* __restrict__ vrt, u16* __restrict__ out)
{
  __shared__ u16 Kt[64 * 16 * 8];  // chunk(kp,dq) at kp*16 + (dq^(kp&15))   16KB
  __shared__ u16 Vt[8][128][8];    // [kq][d][j] = V[kb+kq*8+j][d]           16KB
  __shared__ u16 Pa[4][8][16][8];  // [wave][kq][q][j] = P[q][kq*8+j]         8KB

  const int t = threadIdx.x;
  const int lane = t & 63, w = t >> 6;
  const int quad = lane >> 4, lm = lane & 15;
  const int bx = blockIdx.x;           // 0..1023
  const int bh = bx & 31;              // all-heavy-first across bh
  const int qt = 31 - (bx >> 5);
  const int b = bh >> 4, h = bh & 15;
  const int q0 = qt * 64;
  const int qw = q0 + w * 16;

  // Q A-fragments in registers: Q[qw+lm][dc*32+quad*8+j]
  bf16x8 qf[4];
  {
    const u16* qsrc = qkv + (size_t)(b * SS + qw + lm) * 6144 + h * 128 + quad * 8;
#pragma unroll
    for (int dc = 0; dc < 4; ++dc) qf[dc] = *(const bf16x8*)(qsrc + dc * 32);
  }

  f32x4 Oa[8] = {};                 // [dt]: O[q=quad*4+reg][d=dt*16+lm]
  float mrow[4], lrow[4];
#pragma unroll
  for (int r = 0; r < 4; ++r) { mrow[r] = -1e30f; lrow[r] = 0.f; }

  const float scale = 0.08838834764831845f;  // 1/sqrt(128)
  const int nkt = qt + 1;
  const u16* kbase = qkv + (size_t)b * SS * 6144 + 2048 + h * 128;
  const u16* vbase = vrt + (size_t)bh * 128 * 2048;

  for (int kt = 0; kt < nkt; ++kt) {
    const int kb = kt * 64;
    __syncthreads();
    // stage K (64 rows x 256B, row-coalesced) and V^T (128 rows x 128B)
#pragma unroll
    for (int it = 0; it < 4; ++it) {
      int c = t + it * 256;
      int kp = c >> 4, dq = c & 15;
      *(uint4*)&Kt[(size_t)(kp * 16 + (dq ^ (kp & 15))) * 8] =
          *(const uint4*)(kbase + (size_t)(kb + kp) * 6144 + dq * 8);
      int d = c >> 3, kq = c & 7;
      *(uint4*)&Vt[kq][d][0] =
          *(const uint4*)(vbase + (size_t)d * 2048 + kb + kq * 8);
    }
    __syncthreads();

    // S = Q K^T : per wave 16 q x 64 kp
    f32x4 sa[4] = {};
#pragma unroll
    for (int ct = 0; ct < 4; ++ct) {
#pragma unroll
      for (int dc = 0; dc < 4; ++dc) {
        bf16x8 kf = *(const bf16x8*)&Kt[(size_t)((ct * 16 + lm) * 16 +
                                                 ((dc * 4 + quad) ^ lm)) * 8];
        sa[ct] = __builtin_amdgcn_mfma_f32_16x16x32_bf16(qf[dc], kf, sa[ct], 0, 0, 0);
      }
    }
#pragma unroll
    for (int ct = 0; ct < 4; ++ct)
#pragma unroll
      for (int r = 0; r < 4; ++r) sa[ct][r] *= scale;

    if (kt == nkt - 1) {  // diagonal tile: mask kpos > qrow
#pragma unroll
      for (int ct = 0; ct < 4; ++ct) {
        int kpos = kb + ct * 16 + lm;
#pragma unroll
        for (int r = 0; r < 4; ++r)
          if (kpos > qw + quad * 4 + r) sa[ct][r] = -1e30f;
      }
    }

    // online softmax: rows = (quad, r); 16 lanes of a quad share 64 cols
    float alpha[4];
#pragma unroll
    for (int r = 0; r < 4; ++r) {
      float mx = fmaxf(fmaxf(sa[0][r], sa[1][r]), fmaxf(sa[2][r], sa[3][r]));
#pragma unroll
      for (int off = 1; off < 16; off <<= 1)
        mx = fmaxf(mx, __shfl_xor(mx, off, 64));
      float mnew = fmaxf(mrow[r], mx);
      alpha[r] = __expf(mrow[r] - mnew);
      float s = 0.f;
#pragma unroll
      for (int ct = 0; ct < 4; ++ct) {
        float p = __expf(sa[ct][r] - mnew);
        sa[ct][r] = p;
        s += p;
      }
#pragma unroll
      for (int off = 1; off < 16; off <<= 1)
        s += __shfl_xor(s, off, 64);
      lrow[r] = lrow[r] * alpha[r] + s;
      mrow[r] = mnew;
    }

#pragma unroll
    for (int dt = 0; dt < 8; ++dt)
#pragma unroll
      for (int r = 0; r < 4; ++r) Oa[dt][r] *= alpha[r];

    // P (C-layout) -> LDS A-frag-major (wave-private, no barrier)
#pragma unroll
    for (int ct = 0; ct < 4; ++ct) {
      int kq = ct * 2 + (lm >> 3), j = lm & 7;
#pragma unroll
      for (int r = 0; r < 4; ++r)
        Pa[w][kq][quad * 4 + r][j] = f2b(sa[ct][r]);
    }
    bf16x8 pf0 = *(const bf16x8*)&Pa[w][quad][lm][0];
    bf16x8 pf1 = *(const bf16x8*)&Pa[w][4 + quad][lm][0];

    // O += P V
#pragma unroll
    for (int dt = 0; dt < 8; ++dt) {
      bf16x8 vf0 = *(const bf16x8*)&Vt[quad][dt * 16 + lm][0];
      bf16x8 vf1 = *(const bf16x8*)&Vt[4 + quad][dt * 16 + lm][0];
      Oa[dt] = __builtin_amdgcn_mfma_f32_16x16x32_bf16(pf0, vf0, Oa[dt], 0, 0, 0);
      Oa[dt] = __builtin_amdgcn_mfma_f32_16x16x32_bf16(pf1, vf1, Oa[dt], 0, 0, 0);
    }
  }

  float inv[4];
#pragma unroll
  for (int r = 0; r < 4; ++r) inv[r] = 1.0f / lrow[r];
  u16* dst = out + (size_t)(b * SS + qw + quad * 4) * 2048 + h * 128 + lm;
#pragma unroll
  for (int r = 0; r < 4; ++r)
#pragma unroll
    for (int dt = 0; dt < 8; ++dt)
      dst[(size_t)r * 2048 + dt * 16] = f2b(Oa[dt][r] * inv[r]);
}

extern "C" void kernel_launch(void* const* d_in, const int* in_sizes, int n_in,
                              void* d_out, int out_size, void* d_ws, size_t ws_size,
                              hipStream_t stream)
{
  (void)in_sizes; (void)n_in; (void)out_size; (void)ws_size;
  const float* X    = (const float*)d_in[0];
  const float* Wqkv = (const float*)d_in[1];
  const float* bqkv = (const float*)d_in[2];
  const float* Wc   = (const float*)d_in[3];
  const float* bc   = (const float*)d_in[4];
  const float* Wr   = (const float*)d_in[5];
  const float* br   = (const float*)d_in[6];
  const float* Wd   = (const float*)d_in[7];
  const float* bd   = (const float*)d_in[8];
  float* out = (float*)d_out;

  char* ws = (char*)d_ws;
  u16* QKV   = (u16*)(ws);
  u16* Xb    = (u16*)(ws + 50331648);
  u16* Vr    = (u16*)(ws + 50331648);
  u16* AO    = (u16*)(ws + 50331648);
  u16* Wqkvb = (u16*)(ws + 67108864);
  u16* VrT   = (u16*)(ws + 67108864);
  u16* Wcb   = (u16*)(ws + 92274688);
  u16* Wrb   = (u16*)(ws + 93585408);
  u16* Cb    = (u16*)(ws + 94896128);
  u16* Wdb   = (u16*)(ws + 97517568);

  dim3 blk(256);

  // 0. convert f32 inputs -> bf16
  cvt_kernel<<<dim3(512, 5), blk, 0, stream>>>(
      X, Xb, 4096 * 2048,
      Wqkv, Wqkvb, 6144 * 2048,
      Wc, Wcb, 320 * 2048,
      Wr, Wrb, 2048 * 320,
      Wd, Wdb, 2048 * 2048);

  // 1. QKV projection
  gemm_bias_kernel<0><<<dim3(48, 32), blk, 0, stream>>>(Xb, Wqkvb, bqkv, QKV,
                                                        4096, 6144, 2048, 2048, 2048, 6144);
  // 2. RoPE in place on q,k
  rope_kernel<<<dim3(4096), blk, 0, stream>>>(QKV);
  // 3. C = V_hidden @ Wc^T + bc
  gemm_bias_kernel<0><<<dim3(3, 32), blk, 0, stream>>>(QKV + 4096, Wcb, bc, Cb,
                                                       4096, 320, 2048, 6144, 2048, 320);
  // 4. Vr = C @ Wr^T + br
  gemm_bias_kernel<0><<<dim3(16, 32), blk, 0, stream>>>(Cb, Wrb, br, Vr,
                                                        4096, 2048, 320, 320, 320, 2048);
  // T. transpose V for attention B-fragments
  transpose_v_kernel<<<dim3(32, 2, 32), blk, 0, stream>>>(Vr, VrT);
  // 5. MFMA causal flash attention -> AO (bf16, hidden layout)
  attn_mfma_kernel<<<dim3(1024), blk, 0, stream>>>(QKV, VrT, AO);
  // 6. output projection -> f32 d_out
  gemm_bias_kernel<1><<<dim3(16, 32), blk, 0, stream>>>(AO, Wdb, bd, out,
                                                        4096, 2048, 2048, 2048, 2048, 2048);
}

// Round 5
// 539.421 us; speedup vs baseline: 5.2477x; 1.2470x over previous
//
#include <hip/hip_runtime.h>

typedef unsigned short u16;
typedef unsigned int u32;
typedef __bf16 bf16x8 __attribute__((ext_vector_type(8)));
typedef float f32x4 __attribute__((ext_vector_type(4)));

#define BB 2
#define SS 2048
#define HH 2048
#define NHH 16
#define HDD 128

__device__ __forceinline__ float b2f(u16 u) {
  union { u32 i; float f; } v; v.i = ((u32)u) << 16; return v.f;
}
__device__ __forceinline__ u16 f2b(float f) {
  union { float f; u32 i; } v; v.f = f;
  u32 x = v.i;
  u32 r = (x + 0x7fffu + ((x >> 16) & 1u)) >> 16;
  return (u16)r;
}

// async global->LDS 16B: LDS dest = wave-uniform base + lane*16
__device__ __forceinline__ void gload_lds16(const u16* g, u16* l) {
  __builtin_amdgcn_global_load_lds(
      (const __attribute__((address_space(1))) u32*)g,
      (__attribute__((address_space(3))) u32*)l, 16, 0, 0);
}

// Fused f32 -> bf16 conversion for 5 tensors; blockIdx.y selects tensor.
__global__ __launch_bounds__(256) void cvt_kernel(
    const float* __restrict__ s0, u16* __restrict__ d0, int n0,
    const float* __restrict__ s1, u16* __restrict__ d1, int n1,
    const float* __restrict__ s2, u16* __restrict__ d2, int n2,
    const float* __restrict__ s3, u16* __restrict__ d3, int n3,
    const float* __restrict__ s4, u16* __restrict__ d4, int n4)
{
  const float* s; u16* d; int n;
  switch (blockIdx.y) {
    case 0: s = s0; d = d0; n = n0; break;
    case 1: s = s1; d = d1; n = n1; break;
    case 2: s = s2; d = d2; n = n2; break;
    case 3: s = s3; d = d3; n = n3; break;
    default: s = s4; d = d4; n = n4; break;
  }
  int nq = n >> 2;
  for (int q = blockIdx.x * 256 + threadIdx.x; q < nq; q += gridDim.x * 256) {
    float4 v = *(const float4*)(s + (size_t)q * 4);
    ushort4 o;
    o.x = f2b(v.x); o.y = f2b(v.y); o.z = f2b(v.z); o.w = f2b(v.w);
    *(ushort4*)(d + (size_t)q * 4) = o;
  }
}

// C = A[M,K](bf16) @ Bw[N,K](bf16)^T + bias(f32). OUT_F32 ? f32 : bf16 store.
// 128x128 tile, BK=32, 256 thr = 4 waves. Row-coalesced global_load_lds staging:
// each gload reads 16 rows x one full 64B line; LDS row-major [row][4x16B] with
// XOR swizzle chunk = c ^ (r&3) ^ ((r>>2)&3) applied on the global column so
// frag ds_read_b128 stays <=2-way banked (free).
template<int OUT_F32>
__global__ __launch_bounds__(256) void gemm_bias_kernel(
    const u16* __restrict__ A, const u16* __restrict__ Bw,
    const float* __restrict__ bias, void* __restrict__ Cv,
    int M, int N, int K, int lda, int ldb, int ldc)
{
  __shared__ u16 Asf[128 * 4 * 8];   // [row][chunk][8]  8KB
  __shared__ u16 Bsf[128 * 4 * 8];
  const int t = threadIdx.x;
  const int m0 = blockIdx.y * 128;
  const int n0 = blockIdx.x * 128;
  const int lane = t & 63, wid = t >> 6;
  const int wm = (wid >> 1) * 64, wn = (wid & 1) * 64;
  const int quad = lane >> 4, lm = lane & 15;

  // staging lane decomposition: lane = r16*4 + c  (16 rows x 4 chunks per gload)
  const int r16 = lane >> 2;
  const int swz = ((lane >> 2) & 3) ^ ((lane >> 4) & 3);
  const int kc = ((lane & 3) ^ swz) * 8;     // swizzled k-chunk (element offset)
  // frag-read swizzle (row bits 0..3 == lm)
  const int fswz = (lm & 3) ^ ((lm >> 2) & 3);

  f32x4 acc[4][4] = {};

  for (int k0 = 0; k0 < K; k0 += 32) {
    __syncthreads();
#pragma unroll
    for (int it = 0; it < 2; ++it) {
      int g = wid * 2 + it;                  // 16-row group 0..7
      int r = g * 16 + r16;
      gload_lds16(A + (size_t)(m0 + r) * lda + k0 + kc, &Asf[(size_t)g * 512]);
      gload_lds16(Bw + (size_t)(n0 + r) * ldb + k0 + kc, &Bsf[(size_t)g * 512]);
    }
    __syncthreads();
    bf16x8 af[4], bf[4];
#pragma unroll
    for (int i = 0; i < 4; ++i) {
      int row = wm + i * 16 + lm;
      af[i] = *(const bf16x8*)&Asf[(size_t)(row * 4 + (quad ^ fswz)) * 8];
    }
#pragma unroll
    for (int j = 0; j < 4; ++j) {
      int row = wn + j * 16 + lm;
      bf[j] = *(const bf16x8*)&Bsf[(size_t)(row * 4 + (quad ^ fswz)) * 8];
    }
#pragma unroll
    for (int i = 0; i < 4; ++i)
#pragma unroll
      for (int j = 0; j < 4; ++j)
        acc[i][j] = __builtin_amdgcn_mfma_f32_16x16x32_bf16(af[i], bf[j], acc[i][j], 0, 0, 0);
  }

#pragma unroll
  for (int i = 0; i < 4; ++i) {
    int gm = m0 + wm + i * 16 + quad * 4;
#pragma unroll
    for (int j = 0; j < 4; ++j) {
      int gn = n0 + wn + j * 16 + lm;
      if (gn < N) {
        float bsv = bias[gn];
        f32x4 a = acc[i][j];
        if (OUT_F32) {
          float* C = (float*)Cv;
#pragma unroll
          for (int rg = 0; rg < 4; ++rg)
            C[(size_t)(gm + rg) * ldc + gn] = a[rg] + bsv;
        } else {
          u16* C = (u16*)Cv;
#pragma unroll
          for (int rg = 0; rg < 4; ++rg)
            C[(size_t)(gm + rg) * ldc + gn] = f2b(a[rg] + bsv);
        }
      }
    }
  }
}

// In-place RoPE on q,k first ROT=32 dims of each head.
__global__ __launch_bounds__(256) void rope_kernel(u16* __restrict__ qkv)
{
  int idx = blockIdx.x * 256 + threadIdx.x;   // B*S*NH*16 = 1048576
  int i = idx & 15;
  int h = (idx >> 4) & 15;
  int rs = idx >> 8;
  int s = rs & (SS - 1);
  float inv_freq = exp2f(-(float)i * 0.8304820237218406f);
  float ang = (float)s * inv_freq;
  float sn, c;
  sincosf(ang, &sn, &c);
  size_t base = (size_t)rs * 6144 + (size_t)h * 128;
  {
    float x0 = b2f(qkv[base + i]), x1 = b2f(qkv[base + i + 16]);
    qkv[base + i]      = f2b(x0 * c - x1 * sn);
    qkv[base + i + 16] = f2b(x1 * c + x0 * sn);
  }
  {
    size_t kb = base + 2048;
    float x0 = b2f(qkv[kb + i]), x1 = b2f(qkv[kb + i + 16]);
    qkv[kb + i]      = f2b(x0 * c - x1 * sn);
    qkv[kb + i + 16] = f2b(x1 * c + x0 * sn);
  }
}

// Vr[4096][2048] -> VrT[32][128][2048]: VrT[b*16+h][d][s] = Vr[b*2048+s][h*128+d]
__global__ __launch_bounds__(256) void transpose_v_kernel(const u16* __restrict__ vr,
                                                          u16* __restrict__ vrt)
{
  __shared__ u16 L[64][72];
  const int t = threadIdx.x;
  const int s0 = blockIdx.x * 64;
  const int d0 = blockIdx.y * 64;
  const int bh = blockIdx.z; const int b = bh >> 4, h = bh & 15;
#pragma unroll
  for (int it = 0; it < 2; ++it) {
    int c = t + it * 256;
    int sl = c >> 3, d8 = c & 7;
    *(uint4*)&L[sl][d8 * 8] =
      *(const uint4*)(vr + (size_t)(b * 2048 + s0 + sl) * 2048 + h * 128 + d0 + d8 * 8);
  }
  __syncthreads();
#pragma unroll
  for (int it = 0; it < 2; ++it) {
    int c = t + it * 256;
    int d = c >> 3, s8 = c & 7;
    u16 tmp[8];
#pragma unroll
    for (int r = 0; r < 8; ++r) tmp[r] = L[s8 * 8 + r][d];
    uint4 o;
    o.x = (u32)tmp[0] | ((u32)tmp[1] << 16);
    o.y = (u32)tmp[2] | ((u32)tmp[3] << 16);
    o.z = (u32)tmp[4] | ((u32)tmp[5] << 16);
    o.w = (u32)tmp[6] | ((u32)tmp[7] << 16);
    *(uint4*)(vrt + ((size_t)bh * 128 + d0 + d) * 2048 + s0 + s8 * 8) = o;
  }
}

// MFMA causal flash attention. Block = 4 waves, one (b,h), 64 q-rows.
// K in XOR-swizzled flat LDS; staging row-coalesced.
__global__ __launch_bounds__(256) void attn_mfma_kernel(
    const u16* __restrict__ qkv, const u16* __restrict__ vrt, u16* __restrict__ out)
{
  __shared__ u16 Kt[64 * 16 * 8];  // chunk(kp,dq) at kp*16 + (dq^(kp&15))   16KB
  __shared__ u16 Vt[8][128][8];    // [kq][d][j] = V[kb+kq*8+j][d]           16KB
  __shared__ u16 Pa[4][8][16][8];  // [wave][kq][q][j] = P[q][kq*8+j]         8KB

  const int t = threadIdx.x;
  const int lane = t & 63, w = t >> 6;
  const int quad = lane >> 4, lm = lane & 15;
  const int bx = blockIdx.x;           // 0..1023
  const int bh = bx & 31;
  const int qt = 31 - (bx >> 5);
  const int b = bh >> 4, h = bh & 15;
  const int q0 = qt * 64;
  const int qw = q0 + w * 16;

  bf16x8 qf[4];
  {
    const u16* qsrc = qkv + (size_t)(b * SS + qw + lm) * 6144 + h * 128 + quad * 8;
#pragma unroll
    for (int dc = 0; dc < 4; ++dc) qf[dc] = *(const bf16x8*)(qsrc + dc * 32);
  }

  f32x4 Oa[8] = {};                 // [dt]: O[q=quad*4+reg][d=dt*16+lm]
  float mrow[4], lrow[4];
#pragma unroll
  for (int r = 0; r < 4; ++r) { mrow[r] = -1e30f; lrow[r] = 0.f; }

  const float scale = 0.08838834764831845f;  // 1/sqrt(128)
  const int nkt = qt + 1;
  const u16* kbase = qkv + (size_t)b * SS * 6144 + 2048 + h * 128;
  const u16* vbase = vrt + (size_t)bh * 128 * 2048;

  for (int kt = 0; kt < nkt; ++kt) {
    const int kb = kt * 64;
    __syncthreads();
#pragma unroll
    for (int it = 0; it < 4; ++it) {
      int c = t + it * 256;
      int kp = c >> 4, dq = c & 15;
      *(uint4*)&Kt[(size_t)(kp * 16 + (dq ^ (kp & 15))) * 8] =
          *(const uint4*)(kbase + (size_t)(kb + kp) * 6144 + dq * 8);
      int d = c >> 3, kq = c & 7;
      *(uint4*)&Vt[kq][d][0] =
          *(const uint4*)(vbase + (size_t)d * 2048 + kb + kq * 8);
    }
    __syncthreads();

    f32x4 sa[4] = {};
#pragma unroll
    for (int ct = 0; ct < 4; ++ct) {
#pragma unroll
      for (int dc = 0; dc < 4; ++dc) {
        bf16x8 kf = *(const bf16x8*)&Kt[(size_t)((ct * 16 + lm) * 16 +
                                                 ((dc * 4 + quad) ^ lm)) * 8];
        sa[ct] = __builtin_amdgcn_mfma_f32_16x16x32_bf16(qf[dc], kf, sa[ct], 0, 0, 0);
      }
    }
#pragma unroll
    for (int ct = 0; ct < 4; ++ct)
#pragma unroll
      for (int r = 0; r < 4; ++r) sa[ct][r] *= scale;

    if (kt == nkt - 1) {
#pragma unroll
      for (int ct = 0; ct < 4; ++ct) {
        int kpos = kb + ct * 16 + lm;
#pragma unroll
        for (int r = 0; r < 4; ++r)
          if (kpos > qw + quad * 4 + r) sa[ct][r] = -1e30f;
      }
    }

    float alpha[4];
#pragma unroll
    for (int r = 0; r < 4; ++r) {
      float mx = fmaxf(fmaxf(sa[0][r], sa[1][r]), fmaxf(sa[2][r], sa[3][r]));
#pragma unroll
      for (int off = 1; off < 16; off <<= 1)
        mx = fmaxf(mx, __shfl_xor(mx, off, 64));
      float mnew = fmaxf(mrow[r], mx);
      alpha[r] = __expf(mrow[r] - mnew);
      float s = 0.f;
#pragma unroll
      for (int ct = 0; ct < 4; ++ct) {
        float p = __expf(sa[ct][r] - mnew);
        sa[ct][r] = p;
        s += p;
      }
#pragma unroll
      for (int off = 1; off < 16; off <<= 1)
        s += __shfl_xor(s, off, 64);
      lrow[r] = lrow[r] * alpha[r] + s;
      mrow[r] = mnew;
    }

#pragma unroll
    for (int dt = 0; dt < 8; ++dt)
#pragma unroll
      for (int r = 0; r < 4; ++r) Oa[dt][r] *= alpha[r];

#pragma unroll
    for (int ct = 0; ct < 4; ++ct) {
      int kq = ct * 2 + (lm >> 3), j = lm & 7;
#pragma unroll
      for (int r = 0; r < 4; ++r)
        Pa[w][kq][quad * 4 + r][j] = f2b(sa[ct][r]);
    }
    bf16x8 pf0 = *(const bf16x8*)&Pa[w][quad][lm][0];
    bf16x8 pf1 = *(const bf16x8*)&Pa[w][4 + quad][lm][0];

#pragma unroll
    for (int dt = 0; dt < 8; ++dt) {
      bf16x8 vf0 = *(const bf16x8*)&Vt[quad][dt * 16 + lm][0];
      bf16x8 vf1 = *(const bf16x8*)&Vt[4 + quad][dt * 16 + lm][0];
      Oa[dt] = __builtin_amdgcn_mfma_f32_16x16x32_bf16(pf0, vf0, Oa[dt], 0, 0, 0);
      Oa[dt] = __builtin_amdgcn_mfma_f32_16x16x32_bf16(pf1, vf1, Oa[dt], 0, 0, 0);
    }
  }

  float inv[4];
#pragma unroll
  for (int r = 0; r < 4; ++r) inv[r] = 1.0f / lrow[r];
  u16* dst = out + (size_t)(b * SS + qw + quad * 4) * 2048 + h * 128 + lm;
#pragma unroll
  for (int r = 0; r < 4; ++r)
#pragma unroll
    for (int dt = 0; dt < 8; ++dt)
      dst[(size_t)r * 2048 + dt * 16] = f2b(Oa[dt][r] * inv[r]);
}

extern "C" void kernel_launch(void* const* d_in, const int* in_sizes, int n_in,
                              void* d_out, int out_size, void* d_ws, size_t ws_size,
                              hipStream_t stream)
{
  (void)in_sizes; (void)n_in; (void)out_size; (void)ws_size;
  const float* X    = (const float*)d_in[0];
  const float* Wqkv = (const float*)d_in[1];
  const float* bqkv = (const float*)d_in[2];
  const float* Wc   = (const float*)d_in[3];
  const float* bc   = (const float*)d_in[4];
  const float* Wr   = (const float*)d_in[5];
  const float* br   = (const float*)d_in[6];
  const float* Wd   = (const float*)d_in[7];
  const float* bd   = (const float*)d_in[8];
  float* out = (float*)d_out;

  char* ws = (char*)d_ws;
  u16* QKV   = (u16*)(ws);
  u16* Xb    = (u16*)(ws + 50331648);
  u16* Vr    = (u16*)(ws + 50331648);
  u16* AO    = (u16*)(ws + 50331648);
  u16* Wqkvb = (u16*)(ws + 67108864);
  u16* VrT   = (u16*)(ws + 67108864);
  u16* Wcb   = (u16*)(ws + 92274688);
  u16* Wrb   = (u16*)(ws + 93585408);
  u16* Cb    = (u16*)(ws + 94896128);
  u16* Wdb   = (u16*)(ws + 97517568);

  dim3 blk(256);

  // 0. convert f32 inputs -> bf16
  cvt_kernel<<<dim3(512, 5), blk, 0, stream>>>(
      X, Xb, 4096 * 2048,
      Wqkv, Wqkvb, 6144 * 2048,
      Wc, Wcb, 320 * 2048,
      Wr, Wrb, 2048 * 320,
      Wd, Wdb, 2048 * 2048);

  // 1. QKV projection
  gemm_bias_kernel<0><<<dim3(48, 32), blk, 0, stream>>>(Xb, Wqkvb, bqkv, QKV,
                                                        4096, 6144, 2048, 2048, 2048, 6144);
  // 2. RoPE in place on q,k
  rope_kernel<<<dim3(4096), blk, 0, stream>>>(QKV);
  // 3. C = V_hidden @ Wc^T + bc
  gemm_bias_kernel<0><<<dim3(3, 32), blk, 0, stream>>>(QKV + 4096, Wcb, bc, Cb,
                                                       4096, 320, 2048, 6144, 2048, 320);
  // 4. Vr = C @ Wr^T + br
  gemm_bias_kernel<0><<<dim3(16, 32), blk, 0, stream>>>(Cb, Wrb, br, Vr,
                                                        4096, 2048, 320, 320, 320, 2048);
  // T. transpose V for attention B-fragments
  transpose_v_kernel<<<dim3(32, 2, 32), blk, 0, stream>>>(Vr, VrT);
  // 5. MFMA causal flash attention -> AO (bf16, hidden layout)
  attn_mfma_kernel<<<dim3(1024), blk, 0, stream>>>(QKV, VrT, AO);
  // 6. output projection -> f32 d_out
  gemm_bias_kernel<1><<<dim3(16, 32), blk, 0, stream>>>(AO, Wdb, bd, out,
                                                        4096, 2048, 2048, 2048, 2048, 2048);
}

// Round 6
// 506.897 us; speedup vs baseline: 5.5845x; 1.0642x over previous
//
#include <hip/hip_runtime.h>

typedef unsigned short u16;
typedef unsigned int u32;
typedef __bf16 bf16x8 __attribute__((ext_vector_type(8)));
typedef float f32x4 __attribute__((ext_vector_type(4)));

#define BB 2
#define SS 2048
#define HH 2048
#define NHH 16
#define HDD 128

__device__ __forceinline__ float b2f(u16 u) {
  union { u32 i; float f; } v; v.i = ((u32)u) << 16; return v.f;
}
__device__ __forceinline__ u16 f2b(float f) {
  union { float f; u32 i; } v; v.f = f;
  u32 x = v.i;
  u32 r = (x + 0x7fffu + ((x >> 16) & 1u)) >> 16;
  return (u16)r;
}

// async global->LDS 16B: LDS dest = wave-uniform base + lane*16
__device__ __forceinline__ void gload_lds16(const u16* g, u16* l) {
  __builtin_amdgcn_global_load_lds(
      (const __attribute__((address_space(1))) u32*)g,
      (__attribute__((address_space(3))) u32*)l, 16, 0, 0);
}

// Fused f32 -> bf16 conversion for 5 tensors; blockIdx.y selects tensor.
__global__ __launch_bounds__(256) void cvt_kernel(
    const float* __restrict__ s0, u16* __restrict__ d0, int n0,
    const float* __restrict__ s1, u16* __restrict__ d1, int n1,
    const float* __restrict__ s2, u16* __restrict__ d2, int n2,
    const float* __restrict__ s3, u16* __restrict__ d3, int n3,
    const float* __restrict__ s4, u16* __restrict__ d4, int n4)
{
  const float* s; u16* d; int n;
  switch (blockIdx.y) {
    case 0: s = s0; d = d0; n = n0; break;
    case 1: s = s1; d = d1; n = n1; break;
    case 2: s = s2; d = d2; n = n2; break;
    case 3: s = s3; d = d3; n = n3; break;
    default: s = s4; d = d4; n = n4; break;
  }
  int nq = n >> 2;
  for (int q = blockIdx.x * 256 + threadIdx.x; q < nq; q += gridDim.x * 256) {
    float4 v = *(const float4*)(s + (size_t)q * 4);
    ushort4 o;
    o.x = f2b(v.x); o.y = f2b(v.y); o.z = f2b(v.z); o.w = f2b(v.w);
    *(ushort4*)(d + (size_t)q * 4) = o;
  }
}

// C = A[M,K](bf16) @ Bw[N,K](bf16)^T + bias(f32). OUT_F32 ? f32 : bf16 store.
// ROPE: fused RoPE on tiles wn==0, j<2, n0<4096 (QKV layout, ldc=6144).
// BIAS_ROW: bias indexed by output row (for transposed-output GEMM).
// blockIdx.z batching via strideB/strideC (elements).
template<int OUT_F32, int ROPE, int BIAS_ROW>
__global__ __launch_bounds__(256) void gemm_bias_kernel(
    const u16* __restrict__ A, const u16* __restrict__ Bw,
    const float* __restrict__ bias, void* __restrict__ Cv,
    int M, int N, int K, int lda, int ldb, int ldc,
    size_t strideB, size_t strideC)
{
  __shared__ u16 Asf[128 * 4 * 8];   // [row][chunk][8]  8KB
  __shared__ u16 Bsf[128 * 4 * 8];
  const int t = threadIdx.x;
  const int m0 = blockIdx.y * 128;
  const int n0 = blockIdx.x * 128;
  const int lane = t & 63, wid = t >> 6;
  const int wm = (wid >> 1) * 64, wn = (wid & 1) * 64;
  const int quad = lane >> 4, lm = lane & 15;

  const u16* Bz = Bw + (size_t)blockIdx.z * strideB;

  // staging lane decomposition: lane = r16*4 + c  (16 rows x 4 chunks per gload)
  const int r16 = lane >> 2;
  const int swz = ((lane >> 2) & 3) ^ ((lane >> 4) & 3);
  const int kc = ((lane & 3) ^ swz) * 8;     // swizzled k-chunk (element offset)
  const int fswz = (lm & 3) ^ ((lm >> 2) & 3);

  f32x4 acc[4][4] = {};

  for (int k0 = 0; k0 < K; k0 += 32) {
    __syncthreads();
#pragma unroll
    for (int it = 0; it < 2; ++it) {
      int g = wid * 2 + it;                  // 16-row group 0..7
      int r = g * 16 + r16;
      gload_lds16(A + (size_t)(m0 + r) * lda + k0 + kc, &Asf[(size_t)g * 512]);
      gload_lds16(Bz + (size_t)(n0 + r) * ldb + k0 + kc, &Bsf[(size_t)g * 512]);
    }
    __syncthreads();
    bf16x8 af[4], bf[4];
#pragma unroll
    for (int i = 0; i < 4; ++i) {
      int row = wm + i * 16 + lm;
      af[i] = *(const bf16x8*)&Asf[(size_t)(row * 4 + (quad ^ fswz)) * 8];
    }
#pragma unroll
    for (int j = 0; j < 4; ++j) {
      int row = wn + j * 16 + lm;
      bf[j] = *(const bf16x8*)&Bsf[(size_t)(row * 4 + (quad ^ fswz)) * 8];
    }
#pragma unroll
    for (int i = 0; i < 4; ++i)
#pragma unroll
      for (int j = 0; j < 4; ++j)
        acc[i][j] = __builtin_amdgcn_mfma_f32_16x16x32_bf16(af[i], bf[j], acc[i][j], 0, 0, 0);
  }

  float* Cf = (float*)Cv + (OUT_F32 ? (size_t)blockIdx.z * strideC : 0);
  u16* Cu = (u16*)Cv + (OUT_F32 ? 0 : (size_t)blockIdx.z * strideC);
  const float ropefreq = ROPE ? exp2f(-(float)lm * 0.8304820237218406f) : 0.f;
  const bool do_rope = ROPE && (wn == 0) && (n0 < 4096);

#pragma unroll
  for (int i = 0; i < 4; ++i) {
    int gm = m0 + wm + i * 16 + quad * 4;
    int jstart = 0;
    if (do_rope) {
      jstart = 2;
      int gn0 = n0 + lm, gn1 = gn0 + 16;
      float b0 = bias[gn0], b1 = bias[gn1];
#pragma unroll
      for (int rg = 0; rg < 4; ++rg) {
        int rs = gm + rg;
        float sn, cs;
        sincosf((float)(rs & (SS - 1)) * ropefreq, &sn, &cs);
        float x0 = acc[i][0][rg] + b0, x1 = acc[i][1][rg] + b1;
        Cu[(size_t)rs * ldc + gn0] = f2b(x0 * cs - x1 * sn);
        Cu[(size_t)rs * ldc + gn1] = f2b(x1 * cs + x0 * sn);
      }
    }
#pragma unroll
    for (int j = 0; j < 4; ++j) {
      if (j < jstart) continue;
      int gn = n0 + wn + j * 16 + lm;
      if (gn < N) {
        f32x4 a = acc[i][j];
#pragma unroll
        for (int rg = 0; rg < 4; ++rg) {
          float bsv = BIAS_ROW ? bias[gm + rg] : bias[gn];
          if (OUT_F32) Cf[(size_t)(gm + rg) * ldc + gn] = a[rg] + bsv;
          else         Cu[(size_t)(gm + rg) * ldc + gn] = f2b(a[rg] + bsv);
        }
      }
    }
  }
}

// MFMA causal flash attention, S^T formulation. Block = 4 waves, one (b,h),
// 64 q-rows (wave w: qw..qw+15). S^T = K·Q^T puts softmax rows per-lane
// (q = lane&15): in-register reduce + 2 shfl. P packed to LDS via 4x b64.
__global__ __launch_bounds__(256) void attn_mfma_kernel(
    const u16* __restrict__ qkv, const u16* __restrict__ vrt, u16* __restrict__ out)
{
  __shared__ u16 Kt[64 * 16 * 8];  // chunk(kp,dq) at kp*16 + (dq^(kp&15))   16KB
  __shared__ u16 Vt[8][128][8];    // [kq][d][j] = V[kb+kq*8+j][d]           16KB
  __shared__ u16 Pa[4][16 * 64];   // [w][q*64 + unit-swizzled]               8KB

  const int t = threadIdx.x;
  const int lane = t & 63, w = t >> 6;
  const int quad = lane >> 4, lm = lane & 15;
  const int bx = blockIdx.x;           // 0..1023
  const int bh = bx & 31;
  const int qt = 31 - (bx >> 5);
  const int b = bh >> 4, h = bh & 15;
  const int q0 = qt * 64;
  const int qw = q0 + w * 16;

  // Q fragments (B-operand now; same data layout): Q[qw+lm][dc*32+quad*8+j]
  bf16x8 qf[4];
  {
    const u16* qsrc = qkv + (size_t)(b * SS + qw + lm) * 6144 + h * 128 + quad * 8;
#pragma unroll
    for (int dc = 0; dc < 4; ++dc) qf[dc] = *(const bf16x8*)(qsrc + dc * 32);
  }

  f32x4 Oa[8] = {};                 // [dt]: O[q=quad*4+r][d=dt*16+lm]
  float m_i = -1e30f, l_i = 0.f;    // per-lane softmax state for q = qw+lm

  const float scale = 0.08838834764831845f;  // 1/sqrt(128)
  const int nkt = qt + 1;
  const u16* kbase = qkv + (size_t)b * SS * 6144 + 2048 + h * 128;
  const u16* vbase = vrt + (size_t)bh * 128 * 2048;
  u16* pw = &Pa[w][0];

  for (int kt = 0; kt < nkt; ++kt) {
    const int kb = kt * 64;
    __syncthreads();
#pragma unroll
    for (int it = 0; it < 4; ++it) {
      int c = t + it * 256;
      int kp = c >> 4, dq = c & 15;
      *(uint4*)&Kt[(size_t)(kp * 16 + (dq ^ (kp & 15))) * 8] =
          *(const uint4*)(kbase + (size_t)(kb + kp) * 6144 + dq * 8);
      int d = c >> 3, kq = c & 7;
      *(uint4*)&Vt[kq][d][0] =
          *(const uint4*)(vbase + (size_t)d * 2048 + kb + kq * 8);
    }
    __syncthreads();

    // S^T = K Q^T : C-layout col = q (lane&15), row = kpos_local = quad*4+r
    f32x4 sa[4] = {};
#pragma unroll
    for (int ct = 0; ct < 4; ++ct) {
#pragma unroll
      for (int dc = 0; dc < 4; ++dc) {
        bf16x8 kf = *(const bf16x8*)&Kt[(size_t)((ct * 16 + lm) * 16 +
                                                 ((dc * 4 + quad) ^ lm)) * 8];
        sa[ct] = __builtin_amdgcn_mfma_f32_16x16x32_bf16(kf, qf[dc], sa[ct], 0, 0, 0);
      }
    }
#pragma unroll
    for (int ct = 0; ct < 4; ++ct)
#pragma unroll
      for (int r = 0; r < 4; ++r) sa[ct][r] *= scale;

    if (kt == nkt - 1) {  // diagonal tile: mask kpos > q
      int qpos = qw + lm;
#pragma unroll
      for (int ct = 0; ct < 4; ++ct) {
#pragma unroll
        for (int r = 0; r < 4; ++r)
          if (kb + ct * 16 + quad * 4 + r > qpos) sa[ct][r] = -1e30f;
      }
    }

    // online softmax, per-lane row q = qw+lm (16 vals in-lane + quads via 2 shfl)
    float mx = sa[0][0];
#pragma unroll
    for (int ct = 0; ct < 4; ++ct)
#pragma unroll
      for (int r = 0; r < 4; ++r) mx = fmaxf(mx, sa[ct][r]);
    mx = fmaxf(mx, __shfl_xor(mx, 16, 64));
    mx = fmaxf(mx, __shfl_xor(mx, 32, 64));
    float mnew = fmaxf(m_i, mx);
    float alpha = __expf(m_i - mnew);
    float ssum = 0.f;
#pragma unroll
    for (int ct = 0; ct < 4; ++ct)
#pragma unroll
      for (int r = 0; r < 4; ++r) {
        float p = __expf(sa[ct][r] - mnew);
        sa[ct][r] = p;
        ssum += p;
      }
    ssum += __shfl_xor(ssum, 16, 64);
    ssum += __shfl_xor(ssum, 32, 64);
    l_i = l_i * alpha + ssum;
    m_i = mnew;

    // redistribute alpha to O rows (q = quad*4+r held at lane lm' = quad*4+r)
    float ar[4];
#pragma unroll
    for (int r = 0; r < 4; ++r) ar[r] = __shfl(alpha, quad * 4 + r, 64);
#pragma unroll
    for (int dt = 0; dt < 8; ++dt)
#pragma unroll
      for (int r = 0; r < 4; ++r) Oa[dt][r] *= ar[r];

    // P^T (C-layout) -> Pa A-frag layout: row q=lm, unit u (16B of 8 kpos)
    // stored at u^(lm&7); write 8B halves (kpos = ct*16+quad*4 .. +3)
#pragma unroll
    for (int ct = 0; ct < 4; ++ct) {
      uint2 pk;
      pk.x = (u32)f2b(sa[ct][0]) | ((u32)f2b(sa[ct][1]) << 16);
      pk.y = (u32)f2b(sa[ct][2]) | ((u32)f2b(sa[ct][3]) << 16);
      int u = ct * 2 + (quad >> 1);
      *(uint2*)(pw + lm * 64 + ((u ^ (lm & 7)) * 8) + (quad & 1) * 4) = pk;
    }
    bf16x8 pf0 = *(const bf16x8*)(pw + lm * 64 + ((quad ^ (lm & 7)) * 8));
    bf16x8 pf1 = *(const bf16x8*)(pw + lm * 64 + (((4 + quad) ^ (lm & 7)) * 8));

    // O += P V
#pragma unroll
    for (int dt = 0; dt < 8; ++dt) {
      bf16x8 vf0 = *(const bf16x8*)&Vt[quad][dt * 16 + lm][0];
      bf16x8 vf1 = *(const bf16x8*)&Vt[4 + quad][dt * 16 + lm][0];
      Oa[dt] = __builtin_amdgcn_mfma_f32_16x16x32_bf16(pf0, vf0, Oa[dt], 0, 0, 0);
      Oa[dt] = __builtin_amdgcn_mfma_f32_16x16x32_bf16(pf1, vf1, Oa[dt], 0, 0, 0);
    }
  }

  float inv = 1.0f / l_i;
  float ir[4];
#pragma unroll
  for (int r = 0; r < 4; ++r) ir[r] = __shfl(inv, quad * 4 + r, 64);
  u16* dst = out + (size_t)(b * SS + qw + quad * 4) * 2048 + h * 128 + lm;
#pragma unroll
  for (int r = 0; r < 4; ++r)
#pragma unroll
    for (int dt = 0; dt < 8; ++dt)
      dst[(size_t)r * 2048 + dt * 16] = f2b(Oa[dt][r] * ir[r]);
}

extern "C" void kernel_launch(void* const* d_in, const int* in_sizes, int n_in,
                              void* d_out, int out_size, void* d_ws, size_t ws_size,
                              hipStream_t stream)
{
  (void)in_sizes; (void)n_in; (void)out_size; (void)ws_size;
  const float* X    = (const float*)d_in[0];
  const float* Wqkv = (const float*)d_in[1];
  const float* bqkv = (const float*)d_in[2];
  const float* Wc   = (const float*)d_in[3];
  const float* bc   = (const float*)d_in[4];
  const float* Wr   = (const float*)d_in[5];
  const float* br   = (const float*)d_in[6];
  const float* Wd   = (const float*)d_in[7];
  const float* bd   = (const float*)d_in[8];
  float* out = (float*)d_out;

  char* ws = (char*)d_ws;
  u16* QKV   = (u16*)(ws);                  // 50,331,648 B      [1-5]
  u16* Xb    = (u16*)(ws + 50331648);       // 16 MB  [cvt-1]
  u16* AO    = (u16*)(ws + 50331648);       //        [5-6]
  u16* Wqkvb = (u16*)(ws + 67108864);       // 24 MB  [cvt-1]
  u16* VrT   = (u16*)(ws + 67108864);       // 16 MB  [4-5]
  u16* Wcb   = (u16*)(ws + 92274688);
  u16* Wrb   = (u16*)(ws + 93585408);
  u16* Cb    = (u16*)(ws + 94896128);
  u16* Wdb   = (u16*)(ws + 97517568);

  dim3 blk(256);

  // 0. convert f32 inputs -> bf16
  cvt_kernel<<<dim3(512, 5), blk, 0, stream>>>(
      X, Xb, 4096 * 2048,
      Wqkv, Wqkvb, 6144 * 2048,
      Wc, Wcb, 320 * 2048,
      Wr, Wrb, 2048 * 320,
      Wd, Wdb, 2048 * 2048);

  // 1. QKV projection with fused RoPE
  gemm_bias_kernel<0, 1, 0><<<dim3(48, 32), blk, 0, stream>>>(
      Xb, Wqkvb, bqkv, QKV, 4096, 6144, 2048, 2048, 2048, 6144, 0, 0);
  // 2. C = V_hidden @ Wc^T + bc
  gemm_bias_kernel<0, 0, 0><<<dim3(3, 32), blk, 0, stream>>>(
      QKV + 4096, Wcb, bc, Cb, 4096, 320, 2048, 6144, 2048, 320, 0, 0);
  // 3. VrT = (Cb @ Wr^T)^T + br  == Wr @ Cb^T, per batch (z=2)
  gemm_bias_kernel<0, 0, 1><<<dim3(16, 16, 2), blk, 0, stream>>>(
      Wrb, Cb, br, VrT, 2048, 2048, 320, 320, 320, 2048,
      (size_t)2048 * 320, (size_t)4194304);
  // 4. MFMA causal flash attention -> AO (bf16, hidden layout)
  attn_mfma_kernel<<<dim3(1024), blk, 0, stream>>>(QKV, VrT, AO);
  // 5. output projection -> f32 d_out
  gemm_bias_kernel<1, 0, 0><<<dim3(16, 32), blk, 0, stream>>>(
      AO, Wdb, bd, out, 4096, 2048, 2048, 2048, 2048, 2048, 0, 0);
}